// Round 1
// baseline (384.462 us; speedup 1.0000x reference)
//
#include <hip/hip_runtime.h>
#include <math.h>

#define NNODES 8192
#define DIM 256
#define ALPHA 3.0f
#define SLOPE 0.2f
#define LOG2E 1.4426950408889634f

typedef float floatx4 __attribute__((ext_vector_type(4)));  // native vec for nt store

// Monotone order-preserving float<->uint key for atomicMax on floats.
// key(a) < key(b)  <=>  a < b  (for all finite floats). memset-0 init is
// below every real key (smallest finite float maps to 0x00800000).
__device__ __forceinline__ unsigned fkey(float f) {
    unsigned u = __float_as_uint(f);
    return (u & 0x80000000u) ? ~u : (u ^ 0x80000000u);
}
__device__ __forceinline__ float funkey(unsigned k) {
    unsigned u = (k & 0x80000000u) ? (k ^ 0x80000000u) : ~k;
    return __uint_as_float(u);
}

// ---------------------------------------------------------------------------
// Kernel A: per-node scores s1[n] = tanh(a*emb1[idx[n]]) . w[:256]
//                           s2[n] = tanh(a*emb2[idx[n]]) . w[256:]
// One wave (64 lanes) per node; each lane handles 4 contiguous floats.
// Also produces the GLOBAL max of s2 via atomicMax on a uint-encoded float:
// the row max m_i = lr(s1[i]+b+max_j s2[j]) only needs max_j s2[j], which is
// row-independent — computing it here removes an entire pass (loads + barrier
// + 32 regs of liveness) from the row kernel.
// ---------------------------------------------------------------------------
__global__ __launch_bounds__(256) void s_kernel(
    const int* __restrict__ idx,
    const float* __restrict__ e1, const float* __restrict__ e2,
    const float* __restrict__ w,
    float* __restrict__ s1, float* __restrict__ s2,
    unsigned* __restrict__ s2key)
{
    const int waveId = threadIdx.x >> 6;
    const int lane   = threadIdx.x & 63;
    const int node   = (blockIdx.x << 2) + waveId;   // 4 waves/block
    const int row    = idx[node];

    const float4* e1v = (const float4*)(e1 + (size_t)row * DIM);
    const float4* e2v = (const float4*)(e2 + (size_t)row * DIM);
    const float4* w1v = (const float4*)w;
    const float4* w2v = (const float4*)(w + DIM);

    float4 a  = e1v[lane];
    float4 b  = e2v[lane];
    float4 w1 = w1v[lane];
    float4 w2 = w2v[lane];

    float acc1 = tanhf(ALPHA * a.x) * w1.x + tanhf(ALPHA * a.y) * w1.y
               + tanhf(ALPHA * a.z) * w1.z + tanhf(ALPHA * a.w) * w1.w;
    float acc2 = tanhf(ALPHA * b.x) * w2.x + tanhf(ALPHA * b.y) * w2.y
               + tanhf(ALPHA * b.z) * w2.z + tanhf(ALPHA * b.w) * w2.w;

    #pragma unroll
    for (int off = 32; off > 0; off >>= 1) {
        acc1 += __shfl_down(acc1, off);
        acc2 += __shfl_down(acc2, off);
    }
    if (lane == 0) {
        s1[node] = acc1;
        s2[node] = acc2;
        atomicMax(s2key, fkey(acc2));   // one atomic per wave; device scope
    }
}

// ---------------------------------------------------------------------------
// Kernel C: one block per output row.
//   scores[i,j] = leaky_relu(s1[i] + s2[j] + b)   (lr(x) = max(x, 0.2x))
//   m_i = lr(s1[i] + b + s2max_global)   (exact: lr strictly increasing)
//   out[i, idx[j]] = exp(scores - m_i) / sum_j exp(scores - m_i)
//
// Register-lean restructure vs previous version: no max pass (global s2max
// precomputed), no idx prefetch array, no separate v[] — only the 8 float4
// exp results (r[8] = 32 VGPRs) stay live across the single barrier.
// Target <=96 VGPR so 5-6 blocks/CU are resident (was ~3): the store bursts
// from co-resident blocks must tile over the load/reduce phases to keep the
// HBM write pipe saturated (the 1-GiB fills prove 6.4 TB/s is reachable).
// Output stores are nontemporal (pure 256 MB stream, don't evict s2/idx).
// ---------------------------------------------------------------------------
__global__ __launch_bounds__(256) void row_kernel(
    const float* __restrict__ s1, const float* __restrict__ s2,
    const int* __restrict__ idx, const float* __restrict__ att_b,
    const unsigned* __restrict__ s2key,
    float* __restrict__ out)
{
    __shared__ float lds[4];
    const int t    = threadIdx.x;
    const int lane = t & 63;
    const int wv   = t >> 6;
    const int row  = blockIdx.x;

    const float s2max = funkey(*s2key);
    const float base  = s1[row] + att_b[0];
    const float tm    = base + s2max;
    const float m     = fmaxf(tm, SLOPE * tm);   // exact row max of lr(scores)
    const float mexp  = m * LOG2E;

    // exp pass: e = 2^(lr(base+s2)*log2e - m*log2e), accumulate denominator.
    // Keep only the exp results (r[8]) live; s2 values are consumed in-loop.
    const float4* s2v = (const float4*)s2;
    floatx4 r[8];
    float dsum = 0.0f;
    #pragma unroll
    for (int k = 0; k < 8; ++k) {
        float4 v = s2v[k * 256 + t];
        float x0 = base + v.x, x1 = base + v.y;
        float x2 = base + v.z, x3 = base + v.w;
        x0 = fmaxf(x0, SLOPE * x0);
        x1 = fmaxf(x1, SLOPE * x1);
        x2 = fmaxf(x2, SLOPE * x2);
        x3 = fmaxf(x3, SLOPE * x3);
        r[k].x = __builtin_amdgcn_exp2f(fmaf(x0, LOG2E, -mexp));
        r[k].y = __builtin_amdgcn_exp2f(fmaf(x1, LOG2E, -mexp));
        r[k].z = __builtin_amdgcn_exp2f(fmaf(x2, LOG2E, -mexp));
        r[k].w = __builtin_amdgcn_exp2f(fmaf(x3, LOG2E, -mexp));
        dsum += (r[k].x + r[k].y) + (r[k].z + r[k].w);
    }

    // Block-wide sum for the softmax denominator (single barrier in kernel)
    #pragma unroll
    for (int off = 32; off > 0; off >>= 1)
        dsum += __shfl_xor(dsum, off);
    if (lane == 0) lds[wv] = dsum;
    __syncthreads();
    const float denom = (lds[0] + lds[1]) + (lds[2] + lds[3]);
    const float inv = 1.0f / denom;

    // Store pass: out[row, idx[j]] = e/denom. idx re-loaded from L2 here
    // (32 KB/block, L2-resident) instead of pinning 32 VGPRs across the
    // whole kernel. Fast nontemporal float4 path when the 4 indices are the
    // contiguous aligned identity (idx = arange).
    float* orow = out + (size_t)row * NNODES;
    const int4* idxv = (const int4*)idx;
    #pragma unroll
    for (int k = 0; k < 8; ++k) {
        int4 iv = idxv[k * 256 + t];
        floatx4 o;
        o.x = r[k].x * inv;
        o.y = r[k].y * inv;
        o.z = r[k].z * inv;
        o.w = r[k].w * inv;
        const int c0 = (k * 256 + t) * 4;
        if (iv.x == c0 && iv.y == c0 + 1 && iv.z == c0 + 2 && iv.w == c0 + 3) {
            __builtin_nontemporal_store(o, (floatx4*)(orow + c0));
        } else {
            orow[iv.x] = o.x;
            orow[iv.y] = o.y;
            orow[iv.z] = o.z;
            orow[iv.w] = o.w;
        }
    }
}

extern "C" void kernel_launch(void* const* d_in, const int* in_sizes, int n_in,
                              void* d_out, int out_size, void* d_ws, size_t ws_size,
                              hipStream_t stream) {
    const int*   idx   = (const int*)d_in[0];
    const float* emb1  = (const float*)d_in[1];
    const float* emb2  = (const float*)d_in[2];
    const float* att_w = (const float*)d_in[3];
    const float* att_b = (const float*)d_in[4];
    float* out = (float*)d_out;

    float* s1 = (float*)d_ws;                    // 8192 floats
    float* s2 = s1 + NNODES;                     // 8192 floats
    unsigned* s2key = (unsigned*)(s2 + NNODES);  // 1 uint (global max key)

    hipMemsetAsync(s2key, 0, sizeof(unsigned), stream);  // below all real keys
    s_kernel<<<NNODES / 4, 256, 0, stream>>>(idx, emb1, emb2, att_w, s1, s2, s2key);
    row_kernel<<<NNODES, 256, 0, stream>>>(s1, s2, idx, att_b, s2key, out);
}

// Round 2
// 294.952 us; speedup vs baseline: 1.3035x; 1.3035x over previous
//
#include <hip/hip_runtime.h>
#include <math.h>

#define NNODES 8192
#define DIM 256
#define ALPHA 3.0f
#define SLOPE 0.2f
#define LOG2E 1.4426950408889634f

typedef float floatx4 __attribute__((ext_vector_type(4)));  // native vec for nt store

// ---------------------------------------------------------------------------
// Kernel A: per-node scores s1[n] = tanh(a*emb1[idx[n]]) . w[:256]
//                           s2[n] = tanh(a*emb2[idx[n]]) . w[256:]
// One wave (64 lanes) per node; each lane handles 4 contiguous floats.
// (Round-1 lesson: NO single-address atomics here — 8192 same-line
// device-scope atomicMax ops serialized for ~90 us across 8 XCDs.)
// ---------------------------------------------------------------------------
__global__ __launch_bounds__(256) void s_kernel(
    const int* __restrict__ idx,
    const float* __restrict__ e1, const float* __restrict__ e2,
    const float* __restrict__ w,
    float* __restrict__ s1, float* __restrict__ s2)
{
    const int waveId = threadIdx.x >> 6;
    const int lane   = threadIdx.x & 63;
    const int node   = (blockIdx.x << 2) + waveId;   // 4 waves/block
    const int row    = idx[node];

    const float4* e1v = (const float4*)(e1 + (size_t)row * DIM);
    const float4* e2v = (const float4*)(e2 + (size_t)row * DIM);
    const float4* w1v = (const float4*)w;
    const float4* w2v = (const float4*)(w + DIM);

    float4 a  = e1v[lane];
    float4 b  = e2v[lane];
    float4 w1 = w1v[lane];
    float4 w2 = w2v[lane];

    float acc1 = tanhf(ALPHA * a.x) * w1.x + tanhf(ALPHA * a.y) * w1.y
               + tanhf(ALPHA * a.z) * w1.z + tanhf(ALPHA * a.w) * w1.w;
    float acc2 = tanhf(ALPHA * b.x) * w2.x + tanhf(ALPHA * b.y) * w2.y
               + tanhf(ALPHA * b.z) * w2.z + tanhf(ALPHA * b.w) * w2.w;

    #pragma unroll
    for (int off = 32; off > 0; off >>= 1) {
        acc1 += __shfl_down(acc1, off);
        acc2 += __shfl_down(acc2, off);
    }
    if (lane == 0) {
        s1[node] = acc1;
        s2[node] = acc2;
    }
}

// ---------------------------------------------------------------------------
// Kernel B: prep — one block (256 threads, ~3 us) computes:
//   s2max = max_j s2[j]           (row max of lr-scores only needs this)
//   ident = (idx == arange(N))    (decided ONCE, so the row kernel's store
//                                  path carries no idx loads / compares)
// ---------------------------------------------------------------------------
__global__ __launch_bounds__(256) void prep_kernel(
    const float* __restrict__ s2, const int* __restrict__ idx,
    float* __restrict__ s2max_out, int* __restrict__ ident_out)
{
    __shared__ float smax[4];
    __shared__ int   sok[4];
    const int t = threadIdx.x, lane = t & 63, wv = t >> 6;
    const float4* s2v  = (const float4*)s2;
    const int4*   idxv = (const int4*)idx;
    float lmax = -3.402823466e38f;
    int ok = 1;
    #pragma unroll
    for (int k = 0; k < 8; ++k) {
        float4 v = s2v[k * 256 + t];
        lmax = fmaxf(lmax, fmaxf(fmaxf(v.x, v.y), fmaxf(v.z, v.w)));
        int4 iv = idxv[k * 256 + t];
        const int c0 = (k * 256 + t) * 4;
        ok &= (iv.x == c0) & (iv.y == c0 + 1) & (iv.z == c0 + 2) & (iv.w == c0 + 3);
    }
    #pragma unroll
    for (int off = 32; off > 0; off >>= 1) {
        lmax = fmaxf(lmax, __shfl_xor(lmax, off));
        ok &= __shfl_xor(ok, off);
    }
    if (lane == 0) { smax[wv] = lmax; sok[wv] = ok; }
    __syncthreads();
    if (t == 0) {
        *s2max_out = fmaxf(fmaxf(smax[0], smax[1]), fmaxf(smax[2], smax[3]));
        *ident_out = sok[0] & sok[1] & sok[2] & sok[3];
    }
}

// ---------------------------------------------------------------------------
// Kernel C: WAVE-per-row, two-pass, zero-barrier.
//   scores[i,j] = leaky_relu(s1[i] + s2[j] + b)   (lr(x) = max(x, 0.2x))
//   m_i = lr(s1[i] + b + s2max)                   (exact: lr increasing)
//   out[i, arange] = exp(scores - m_i) / sum_j exp(...)
//
// Each 64-lane wave owns one row: 128 cols/lane. Pass 1 accumulates the
// denominator; butterfly shfl_xor broadcasts it to all lanes (no LDS, no
// __syncthreads). Pass 2 RECOMPUTES the exps (bit-identical sequence;
// exp2 is ~free chip-wide) and streams nontemporal float4 stores at
// computed addresses — no loads, no compares on the store path.
// ~40-50 VGPR -> full 32-wave/CU occupancy; store stream shaped like the
// fill kernel that demonstrably hits 6.4 TB/s.
// ---------------------------------------------------------------------------
__global__ __launch_bounds__(256) void row_kernel(
    const float* __restrict__ s1, const float* __restrict__ s2,
    const int* __restrict__ idx, const float* __restrict__ att_b,
    const float* __restrict__ s2max_p, const int* __restrict__ ident_p,
    float* __restrict__ out)
{
    const int lane = threadIdx.x & 63;
    const int wv   = threadIdx.x >> 6;
    const int row  = (blockIdx.x << 2) + wv;   // 4 rows per block

    const float s2max = *s2max_p;
    const int   ident = *ident_p;
    const float base  = s1[row] + att_b[0];
    const float tm    = base + s2max;
    const float m     = fmaxf(tm, SLOPE * tm);   // exact row max of lr(scores)
    const float mexp  = m * LOG2E;

    const float4* s2v = (const float4*)s2;

    // Pass 1: softmax denominator (s2 is 32 KB -> L1-resident per CU)
    float dsum = 0.0f;
    #pragma unroll 4
    for (int k = 0; k < 32; ++k) {
        float4 v = s2v[k * 64 + lane];
        float x0 = base + v.x, x1 = base + v.y;
        float x2 = base + v.z, x3 = base + v.w;
        x0 = fmaxf(x0, SLOPE * x0);
        x1 = fmaxf(x1, SLOPE * x1);
        x2 = fmaxf(x2, SLOPE * x2);
        x3 = fmaxf(x3, SLOPE * x3);
        float e0 = __builtin_amdgcn_exp2f(fmaf(x0, LOG2E, -mexp));
        float e1 = __builtin_amdgcn_exp2f(fmaf(x1, LOG2E, -mexp));
        float e2 = __builtin_amdgcn_exp2f(fmaf(x2, LOG2E, -mexp));
        float e3 = __builtin_amdgcn_exp2f(fmaf(x3, LOG2E, -mexp));
        dsum += (e0 + e1) + (e2 + e3);
    }
    #pragma unroll
    for (int off = 32; off > 0; off >>= 1)
        dsum += __shfl_xor(dsum, off);           // all lanes hold full sum
    const float inv = 1.0f / dsum;

    float* orow = out + (size_t)row * NNODES;

    if (ident) {
        // Fast path: pure computed-address nontemporal stream.
        #pragma unroll 4
        for (int k = 0; k < 32; ++k) {
            float4 v = s2v[k * 64 + lane];
            float x0 = base + v.x, x1 = base + v.y;
            float x2 = base + v.z, x3 = base + v.w;
            x0 = fmaxf(x0, SLOPE * x0);
            x1 = fmaxf(x1, SLOPE * x1);
            x2 = fmaxf(x2, SLOPE * x2);
            x3 = fmaxf(x3, SLOPE * x3);
            floatx4 o;
            o.x = __builtin_amdgcn_exp2f(fmaf(x0, LOG2E, -mexp)) * inv;
            o.y = __builtin_amdgcn_exp2f(fmaf(x1, LOG2E, -mexp)) * inv;
            o.z = __builtin_amdgcn_exp2f(fmaf(x2, LOG2E, -mexp)) * inv;
            o.w = __builtin_amdgcn_exp2f(fmaf(x3, LOG2E, -mexp)) * inv;
            __builtin_nontemporal_store(o, (floatx4*)(orow + (k * 64 + lane) * 4));
        }
    } else {
        // General path: scatter via idx (L1/L2-resident).
        const int4* idxv = (const int4*)idx;
        #pragma unroll 4
        for (int k = 0; k < 32; ++k) {
            float4 v = s2v[k * 64 + lane];
            int4  iv = idxv[k * 64 + lane];
            float x0 = base + v.x, x1 = base + v.y;
            float x2 = base + v.z, x3 = base + v.w;
            x0 = fmaxf(x0, SLOPE * x0);
            x1 = fmaxf(x1, SLOPE * x1);
            x2 = fmaxf(x2, SLOPE * x2);
            x3 = fmaxf(x3, SLOPE * x3);
            orow[iv.x] = __builtin_amdgcn_exp2f(fmaf(x0, LOG2E, -mexp)) * inv;
            orow[iv.y] = __builtin_amdgcn_exp2f(fmaf(x1, LOG2E, -mexp)) * inv;
            orow[iv.z] = __builtin_amdgcn_exp2f(fmaf(x2, LOG2E, -mexp)) * inv;
            orow[iv.w] = __builtin_amdgcn_exp2f(fmaf(x3, LOG2E, -mexp)) * inv;
        }
    }
}

extern "C" void kernel_launch(void* const* d_in, const int* in_sizes, int n_in,
                              void* d_out, int out_size, void* d_ws, size_t ws_size,
                              hipStream_t stream) {
    const int*   idx   = (const int*)d_in[0];
    const float* emb1  = (const float*)d_in[1];
    const float* emb2  = (const float*)d_in[2];
    const float* att_w = (const float*)d_in[3];
    const float* att_b = (const float*)d_in[4];
    float* out = (float*)d_out;

    float* s1    = (float*)d_ws;          // 8192 floats
    float* s2    = s1 + NNODES;           // 8192 floats
    float* s2max = s2 + NNODES;           // 1 float
    int*   ident = (int*)(s2max + 1);     // 1 int

    s_kernel<<<NNODES / 4, 256, 0, stream>>>(idx, emb1, emb2, att_w, s1, s2);
    prep_kernel<<<1, 256, 0, stream>>>(s2, idx, s2max, ident);
    row_kernel<<<NNODES / 4, 256, 0, stream>>>(s1, s2, idx, att_b, s2max, ident, out);
}